// Round 20
// baseline (155.229 us; speedup 1.0000x reference)
//
#include <hip/hip_runtime.h>
#include <hip/hip_bf16.h>

#define IN_F 256
#define OUT_F 128
#define BSH 8
#define BNODES 256          // nodes per bucket = 1<<BSH
#define MAXBUCK 512         // supports n_nodes <= 131072
#define BINB 128            // bin1a/bin1b block count (equal chunking)
#define GEMM_BLOCKS 256
#define BM 32               // gemm rows per tile

typedef short bf16x8 __attribute__((ext_vector_type(8)));
typedef float f32x4 __attribute__((ext_vector_type(4)));
typedef unsigned short us8 __attribute__((ext_vector_type(8)));

__device__ __forceinline__ unsigned short f2bf(float x) {
    union { __hip_bfloat16 b; unsigned short u; } cv;
    cv.b = __float2bfloat16(x);
    return cv.u;
}
__device__ inline float bf2f(unsigned short x) {
    union { unsigned u; float f; } v; v.u = ((unsigned)x) << 16;
    return v.f;
}

// async 16B global -> LDS (DMA; wave-uniform LDS base + lane*16, per-lane gsrc)
__device__ __forceinline__ void gload_lds16(const void* g, void* l) {
    __builtin_amdgcn_global_load_lds(
        (const __attribute__((address_space(1))) unsigned int*)g,
        (__attribute__((address_space(3))) unsigned int*)l,
        16, 0, 0);
}

// ---------------------------------------------------------------------------
// K1 fused: blocks [0, BINB) = bin1a (bucket histogram -> bhist + per-block
// row -> perbhist); blocks [BINB, +128) = wprep (Wt = bf16(W^T)).
// ---------------------------------------------------------------------------
__global__ __launch_bounds__(256) void prep_kernel(const float* __restrict__ W,
                                                   unsigned short* __restrict__ Wt,
                                                   const int* __restrict__ dst,
                                                   int* __restrict__ bhist,
                                                   int* __restrict__ perbhist,
                                                   int n_edges, int nbuck) {
    if ((int)blockIdx.x < BINB) {
        __shared__ int hist[MAXBUCK];
        const int tid = threadIdx.x;
        const int chunk = (n_edges + BINB - 1) / BINB;
        const int lo = blockIdx.x * chunk;
        const int hi = min(lo + chunk, n_edges);

        for (int i = tid; i < MAXBUCK; i += 256) hist[i] = 0;
        __syncthreads();
        for (int e = lo + tid; e < hi; e += 256)
            atomicAdd(&hist[dst[e] >> BSH], 1);
        __syncthreads();
        int* myrow = perbhist + (size_t)blockIdx.x * MAXBUCK;
        for (int i = tid; i < nbuck; i += 256) {
            int c = hist[i];
            myrow[i] = c;
            if (c) atomicAdd(&bhist[i], c);
        }
    } else {
        int n = blockIdx.x - BINB;           // 0..127
        int k = threadIdx.x;                 // 0..255
        Wt[n * IN_F + k] = f2bf(W[k * OUT_F + n]);
    }
}

// ---------------------------------------------------------------------------
// bin1b (1024 thr, BINB blocks): local LDS scan of bhist -> bucket prefix;
// per-block counts from perbhist; reserve via gcur0; single placement pass.
// 128-node->256-node buckets + 128 blocks => (block,bucket) runs of ~128 B:
// each ebuf cache line belongs to ONE block's run (was 32 B runs shared by
// 2+ XCDs -> ~5.5x write amplification, measured 35 MB in round 10).
// ---------------------------------------------------------------------------
__global__ __launch_bounds__(1024) void bin1b_kernel(const int* __restrict__ src,
                                                     const int* __restrict__ dst,
                                                     const int* __restrict__ bhist,
                                                     const int* __restrict__ perbhist,
                                                     int* __restrict__ gcur0,
                                                     unsigned* __restrict__ ebuf,
                                                     int n_edges, int nbuck) {
    __shared__ int scanv[MAXBUCK];
    __shared__ int hist[MAXBUCK];
    __shared__ int lbase[MAXBUCK];
    const int tid = threadIdx.x;
    const int chunk = (n_edges + BINB - 1) / BINB;
    const int lo = blockIdx.x * chunk;
    const int hi = min(lo + chunk, n_edges);

    int own = (tid < nbuck) ? bhist[tid] : 0;
    if (tid < MAXBUCK) scanv[tid] = own;
    __syncthreads();
    #pragma unroll
    for (int off = 1; off < MAXBUCK; off <<= 1) {
        int t = (tid >= off && tid < MAXBUCK) ? scanv[tid - off] : 0;
        __syncthreads();
        if (tid < MAXBUCK) scanv[tid] += t;
        __syncthreads();
    }
    if (tid < MAXBUCK) scanv[tid] -= own;    // exclusive
    __syncthreads();

    if (tid < nbuck) {
        int c = perbhist[(size_t)blockIdx.x * MAXBUCK + tid];
        lbase[tid] = (c > 0) ? (scanv[tid] + atomicAdd(&gcur0[tid], c)) : 0;
        hist[tid] = 0;                       // local cursor
    }
    __syncthreads();
    for (int e = lo + tid; e < hi; e += 1024) {
        int d = dst[e];
        int bkt = d >> BSH;
        int off = atomicAdd(&hist[bkt], 1);
        ebuf[lbase[bkt] + off] = ((unsigned)src[e] << BSH) | (unsigned)(d & (BNODES - 1));
    }
}

// ---------------------------------------------------------------------------
// gemm: h = bf16( feat @ W ), persistent 3-deep async pipeline, 1024 thr,
// 160 KB LDS (As[3] x 32KB + Bs 64KB), counted vmcnt (unchanged, r18).
// ---------------------------------------------------------------------------
__global__ __launch_bounds__(1024) void gemm_mfma(const float* __restrict__ feat,
                                                  const unsigned short* __restrict__ Wt,
                                                  unsigned short* __restrict__ h,
                                                  int n_nodes) {
    __shared__ float As[3][BM * IN_F];            // 3 x 32 KB
    __shared__ unsigned short Bs[OUT_F * IN_F];   // 64 KB  => 160 KB total

    const int tid  = threadIdx.x;
    const int wave = tid >> 6;          // 0..15
    const int lane = tid & 63;
    const int q    = lane >> 4;         // 0..3
    const int rr   = lane & 15;
    const int rowgrp = wave & 1;
    const int colgrp = wave >> 1;

    const int ntiles = (n_nodes + BM - 1) / BM;
    const int nit = ((int)blockIdx.x < ntiles)
                  ? ((ntiles - (int)blockIdx.x + GEMM_BLOCKS - 1) / GEMM_BLOCKS) : 0;

    #pragma unroll
    for (int m = 0; m < 4; ++m) {
        int p   = m * 16 + wave;
        int row = 2 * p + (lane >> 5);
        int ch  = lane & 31;
        gload_lds16(Wt + (size_t)row * IN_F + ((ch ^ (row & 7)) * 8),
                    &Bs[p * 2 * IN_F]);
    }
    #pragma unroll
    for (int pb = 0; pb < 2; ++pb) {
        if (pb < nit) {
            const int R0 = ((int)blockIdx.x + pb * GEMM_BLOCKS) * BM;
            #pragma unroll
            for (int ii = 0; ii < 2; ++ii) {
                int r  = ii * 16 + wave;
                int rg = R0 + r; if (rg >= n_nodes) rg = n_nodes - 1;
                gload_lds16(feat + (size_t)rg * IN_F + ((lane ^ (r & 7)) * 4),
                            &As[pb][r * IN_F]);
            }
        }
    }

    const bf16x8* bsv = reinterpret_cast<const bf16x8*>(Bs);
    const int arow = rowgrp * 16 + rr;
    const int brow = colgrp * 16 + rr;

    int t = (int)blockIdx.x;
    for (int i = 0; i < nit; ++i, t += GEMM_BLOCKS) {
        if (nit < 4)          asm volatile("s_waitcnt vmcnt(0)" ::: "memory");
        else if (i == 0)      asm volatile("s_waitcnt vmcnt(2)" ::: "memory");
        else if (i == 1)      asm volatile("s_waitcnt vmcnt(6)" ::: "memory");
        else if (i < nit - 1) asm volatile("s_waitcnt vmcnt(10)" ::: "memory");
        else                  asm volatile("s_waitcnt vmcnt(8)" ::: "memory");
        __builtin_amdgcn_s_barrier();

        if (i + 2 < nit) {
            const int R0n = (t + 2 * GEMM_BLOCKS) * BM;
            float* dbuf = As[(i + 2) % 3];
            #pragma unroll
            for (int ii = 0; ii < 2; ++ii) {
                int r  = ii * 16 + wave;
                int rg = R0n + r; if (rg >= n_nodes) rg = n_nodes - 1;
                gload_lds16(feat + (size_t)rg * IN_F + ((lane ^ (r & 7)) * 4),
                            &dbuf[r * IN_F]);
            }
        }

        f32x4 acc = (f32x4){0.f, 0.f, 0.f, 0.f};
        const f32x4* ap = reinterpret_cast<const f32x4*>(&As[i % 3][arow * IN_F]);
        #pragma unroll
        for (int k0 = 0; k0 < 8; ++k0) {
            f32x4 a0 = ap[(k0 * 8 + 2 * q)     ^ (rr & 7)];
            f32x4 a1 = ap[(k0 * 8 + 2 * q + 1) ^ (rr & 7)];
            bf16x8 afr;
            afr[0] = (short)f2bf(a0[0]);
            afr[1] = (short)f2bf(a0[1]);
            afr[2] = (short)f2bf(a0[2]);
            afr[3] = (short)f2bf(a0[3]);
            afr[4] = (short)f2bf(a1[0]);
            afr[5] = (short)f2bf(a1[1]);
            afr[6] = (short)f2bf(a1[2]);
            afr[7] = (short)f2bf(a1[3]);
            bf16x8 bfr = bsv[brow * 32 + ((k0 * 4 + q) ^ (brow & 7))];
            acc = __builtin_amdgcn_mfma_f32_16x16x32_bf16(afr, bfr, acc, 0, 0, 0);
        }

        const int orow0 = t * BM + rowgrp * 16 + q * 4;
        const int col   = colgrp * 16 + rr;
        #pragma unroll
        for (int j = 0; j < 4; ++j)
            h[(size_t)(orow0 + j) * OUT_F + col] = f2bf(acc[j]);
    }
}

// ---------------------------------------------------------------------------
// bin2: one block per 256-node bucket, 256 thr = 1 node/thread.
// Local bhist scan (512 entries, 2/thread) -> e0; per-node counts; 256-wide
// scan -> rstart + norm; exact per-node CSR placement. Bucket-local writes.
// ---------------------------------------------------------------------------
__global__ __launch_bounds__(256) void bin2_kernel(const unsigned* __restrict__ ebuf,
                                                   const int* __restrict__ bhist,
                                                   int* __restrict__ rstart,
                                                   float* __restrict__ norm,
                                                   int* __restrict__ eidx,
                                                   int n_nodes, int nbuck) {
    __shared__ int bs[MAXBUCK];
    __shared__ int lcnt[BNODES];
    __shared__ int lex[BNODES];
    __shared__ int sh[256];
    const int tid = threadIdx.x;
    const int node0 = blockIdx.x << BSH;

    {
        int v0 = (2 * tid     < nbuck) ? bhist[2 * tid]     : 0;
        int v1 = (2 * tid + 1 < nbuck) ? bhist[2 * tid + 1] : 0;
        int s = v0 + v1;
        sh[tid] = s;
        __syncthreads();
        #pragma unroll
        for (int off = 1; off < 256; off <<= 1) {
            int t = (tid >= off) ? sh[tid - off] : 0;
            __syncthreads();
            sh[tid] += t;
            __syncthreads();
        }
        int ex = sh[tid] - s;
        bs[2 * tid]     = ex;
        bs[2 * tid + 1] = ex + v0;
    }
    __syncthreads();

    const int e0 = bs[blockIdx.x];
    const int e1 = e0 + bhist[blockIdx.x];

    lcnt[tid] = 0;
    __syncthreads();
    for (int e = e0 + tid; e < e1; e += 256)
        atomicAdd(&lcnt[ebuf[e] & (BNODES - 1)], 1);
    __syncthreads();

    int own = lcnt[tid];
    lex[tid] = own;
    __syncthreads();
    #pragma unroll
    for (int off = 1; off < BNODES; off <<= 1) {
        int t = (tid >= off) ? lex[tid - off] : 0;
        __syncthreads();
        lex[tid] += t;
        __syncthreads();
    }
    {
        int ex = lex[tid] - own;       // exclusive
        lex[tid] = ex;
        int g = node0 + tid;
        if (g <= n_nodes) rstart[g] = e0 + ex;
        if (g < n_nodes) {
            float d = (float)own;
            if (d < 1.0f) d = 1.0f;
            norm[g] = 1.0f / sqrtf(d);
        }
        lcnt[tid] = 0;                 // reuse as cursor
    }
    __syncthreads();

    for (int e = e0 + tid; e < e1; e += 256) {
        unsigned pk = ebuf[e];
        int dl = pk & (BNODES - 1);
        int pos = atomicAdd(&lcnt[dl], 1);
        eidx[e0 + lex[dl] + pos] = (int)(pk >> BSH);
    }
}

// ---------------------------------------------------------------------------
// agg: one wave per dst node, 4 edge-slots x 16 lanes, uniform control flow.
// (unchanged — fabric-limited at ~64 us)
// ---------------------------------------------------------------------------
__global__ __launch_bounds__(256) void agg_kernel(const unsigned short* __restrict__ h,
                                                  const int* __restrict__ eidx,
                                                  const int* __restrict__ rstart,
                                                  const float* __restrict__ norm,
                                                  const float* __restrict__ bias,
                                                  float* __restrict__ out,
                                                  int n_nodes) {
    const int wave = threadIdx.x >> 6;
    const int lane = threadIdx.x & 63;
    const int grp  = lane >> 4;
    const int gl   = lane & 15;
    const int node = blockIdx.x * 4 + wave;
    if (node >= n_nodes) return;

    const int start = rstart[node];
    const int cnt   = rstart[node + 1] - start;
    const unsigned short* __restrict__ hb = h + gl * 8;

    float acc[8] = {0.f, 0.f, 0.f, 0.f, 0.f, 0.f, 0.f, 0.f};

    for (int base = 0; base < cnt; base += 64) {
        const int rem = min(64, cnt - base);
        int   ev = (lane < rem) ? eidx[start + base + lane] : 0;
        float nv = (lane < rem) ? norm[ev] : 0.f;

        int j = 0;
        for (; j + 16 <= rem; j += 16) {
            int   s0 = __shfl(ev, j + grp);
            int   s1 = __shfl(ev, j + grp + 4);
            int   s2 = __shfl(ev, j + grp + 8);
            int   s3 = __shfl(ev, j + grp + 12);
            float n0 = __shfl(nv, j + grp);
            float n1 = __shfl(nv, j + grp + 4);
            float n2 = __shfl(nv, j + grp + 8);
            float n3 = __shfl(nv, j + grp + 12);
            us8 v0 = *reinterpret_cast<const us8*>(hb + (size_t)s0 * OUT_F);
            us8 v1 = *reinterpret_cast<const us8*>(hb + (size_t)s1 * OUT_F);
            us8 v2 = *reinterpret_cast<const us8*>(hb + (size_t)s2 * OUT_F);
            us8 v3 = *reinterpret_cast<const us8*>(hb + (size_t)s3 * OUT_F);
            #pragma unroll
            for (int qq = 0; qq < 8; ++qq) {
                acc[qq] += bf2f(v0[qq]) * n0 + bf2f(v1[qq]) * n1
                         + bf2f(v2[qq]) * n2 + bf2f(v3[qq]) * n3;
            }
        }
        for (; j < rem; j += 4) {
            int   je = j + grp;
            int   jc = min(je, rem - 1);
            int   s  = __shfl(ev, jc);
            float nm = __shfl(nv, jc);
            if (je >= rem) nm = 0.f;
            us8 v = *reinterpret_cast<const us8*>(hb + (size_t)s * OUT_F);
            #pragma unroll
            for (int qq = 0; qq < 8; ++qq)
                acc[qq] += bf2f(v[qq]) * nm;
        }
    }

    #pragma unroll
    for (int qq = 0; qq < 8; ++qq) {
        acc[qq] += __shfl_xor(acc[qq], 16);
        acc[qq] += __shfl_xor(acc[qq], 32);
    }

    if (grp == 0) {
        const float nd = norm[node];
        const float4 b0 = *reinterpret_cast<const float4*>(bias + gl * 8);
        const float4 b1 = *reinterpret_cast<const float4*>(bias + gl * 8 + 4);
        float4 r0, r1;
        r0.x = acc[0] * nd + b0.x;
        r0.y = acc[1] * nd + b0.y;
        r0.z = acc[2] * nd + b0.z;
        r0.w = acc[3] * nd + b0.w;
        r1.x = acc[4] * nd + b1.x;
        r1.y = acc[5] * nd + b1.y;
        r1.z = acc[6] * nd + b1.z;
        r1.w = acc[7] * nd + b1.w;
        float* o = out + (size_t)node * OUT_F + gl * 8;
        *reinterpret_cast<float4*>(o)     = r0;
        *reinterpret_cast<float4*>(o + 4) = r1;
    }
}

// ---------------------------------------------------------------------------
extern "C" void kernel_launch(void* const* d_in, const int* in_sizes, int n_in,
                              void* d_out, int out_size, void* d_ws, size_t ws_size,
                              hipStream_t stream) {
    const float* feat   = (const float*)d_in[0];
    const float* weight = (const float*)d_in[1];
    const float* bias   = (const float*)d_in[2];
    const int*   src    = (const int*)d_in[3];
    const int*   dst    = (const int*)d_in[4];
    float* out = (float*)d_out;

    const int n_nodes = in_sizes[0] / IN_F;
    const int n_edges = in_sizes[3];
    const int nbuck   = (n_nodes + BNODES - 1) >> BSH;

    char* ws = (char*)d_ws;
    size_t off = 0;
    auto alloc = [&](size_t bytes) {
        char* p = ws + off;
        off += (bytes + 15) & ~(size_t)15;
        return p;
    };
    unsigned short* h  = (unsigned short*)alloc((size_t)(n_nodes + BM) * OUT_F * 2); // +BM pad rows
    float* norm        = (float*)alloc((size_t)n_nodes * 4);
    int*   rstart      = (int*)alloc(((size_t)n_nodes + 1) * 4);
    int*   bhist       = (int*)alloc(2 * MAXBUCK * 4);   // bhist | gcur0
    int*   gcur0       = bhist + MAXBUCK;
    int*   perbhist    = (int*)alloc((size_t)BINB * MAXBUCK * 4);  // 256 KB
    unsigned short* Wt = (unsigned short*)alloc((size_t)OUT_F * IN_F * 2);
    unsigned* ebuf     = (unsigned*)alloc((size_t)n_edges * 4);
    int*   eidx        = (int*)alloc((size_t)n_edges * 4);

    hipMemsetAsync(bhist, 0, 2 * MAXBUCK * sizeof(int), stream);
    // K1: bin1a (+perbhist) || wprep
    prep_kernel<<<BINB + OUT_F, 256, 0, stream>>>(weight, Wt, dst, bhist,
                                                  perbhist, n_edges, nbuck);
    // K2: gemm (3-deep counted-vmcnt pipeline, 160 KB LDS)
    gemm_mfma<<<GEMM_BLOCKS, 1024, 0, stream>>>(feat, Wt, h, n_nodes);
    // K3: binning into bucket-grouped ebuf (runs now ~128 B/block/bucket)
    bin1b_kernel<<<BINB, 1024, 0, stream>>>(src, dst, bhist, perbhist,
                                            gcur0, ebuf, n_edges, nbuck);
    // K4: exact CSR
    bin2_kernel<<<nbuck, 256, 0, stream>>>(ebuf, bhist, rstart, norm, eidx,
                                           n_nodes, nbuck);
    // K5: aggregate
    agg_kernel<<<(n_nodes + 3) / 4, 256, 0, stream>>>(h, eidx, rstart, norm, bias, out, n_nodes);
}

// Round 21
// 144.414 us; speedup vs baseline: 1.0749x; 1.0749x over previous
//
#include <hip/hip_runtime.h>
#include <hip/hip_bf16.h>

#define IN_F 256
#define OUT_F 128
#define BSH 7
#define BNODES 128          // nodes per bucket = 1<<BSH
#define MAXBUCK 1024        // supports n_nodes <= 131072
#define BIN1A_BLOCKS 256
#define BIN1B_BLOCKS 256
#define GEMM_BLOCKS 256
#define BM 32               // gemm rows per tile

typedef short bf16x8 __attribute__((ext_vector_type(8)));
typedef float f32x4 __attribute__((ext_vector_type(4)));
typedef unsigned short us8 __attribute__((ext_vector_type(8)));

__device__ __forceinline__ unsigned short f2bf(float x) {
    union { __hip_bfloat16 b; unsigned short u; } cv;
    cv.b = __float2bfloat16(x);
    return cv.u;
}
__device__ inline float bf2f(unsigned short x) {
    union { unsigned u; float f; } v; v.u = ((unsigned)x) << 16;
    return v.f;
}

// async 16B global -> LDS (DMA; wave-uniform LDS base + lane*16, per-lane gsrc)
__device__ __forceinline__ void gload_lds16(const void* g, void* l) {
    __builtin_amdgcn_global_load_lds(
        (const __attribute__((address_space(1))) unsigned int*)g,
        (__attribute__((address_space(3))) unsigned int*)l,
        16, 0, 0);
}

// ---------------------------------------------------------------------------
// K1 fused: blocks [0, BIN1A_BLOCKS) = bin1a (bucket histogram -> bhist AND
// per-block histogram row -> perbhist); blocks [BIN1A_BLOCKS,+128) = wprep.
// (round-18 configuration restored: BSH=7, 256 bin blocks)
// ---------------------------------------------------------------------------
__global__ __launch_bounds__(256) void prep_kernel(const float* __restrict__ W,
                                                   unsigned short* __restrict__ Wt,
                                                   const int* __restrict__ dst,
                                                   int* __restrict__ bhist,
                                                   int* __restrict__ perbhist,
                                                   int n_edges, int nbuck) {
    if ((int)blockIdx.x < BIN1A_BLOCKS) {
        __shared__ int hist[MAXBUCK];
        const int tid = threadIdx.x;
        const int chunk = (n_edges + BIN1A_BLOCKS - 1) / BIN1A_BLOCKS;
        const int lo = blockIdx.x * chunk;
        const int hi = min(lo + chunk, n_edges);

        for (int i = tid; i < MAXBUCK; i += 256) hist[i] = 0;
        __syncthreads();
        for (int e = lo + tid; e < hi; e += 256)
            atomicAdd(&hist[dst[e] >> BSH], 1);
        __syncthreads();
        int* myrow = perbhist + (size_t)blockIdx.x * MAXBUCK;
        for (int i = tid; i < nbuck; i += 256) {
            int c = hist[i];
            myrow[i] = c;
            if (c) atomicAdd(&bhist[i], c);
        }
    } else {
        int n = blockIdx.x - BIN1A_BLOCKS;   // 0..127
        int k = threadIdx.x;                 // 0..255
        Wt[n * IN_F + k] = f2bf(W[k * OUT_F + n]);
    }
}

// ---------------------------------------------------------------------------
// bin1b (1024 thr): local LDS scan of bhist -> bucket prefix; per-block
// counts from perbhist (count pass eliminated); reserve via gcur0; single
// placement pass into bucket-grouped ebuf. (round-18 verbatim)
// ---------------------------------------------------------------------------
__global__ __launch_bounds__(1024) void bin1b_kernel(const int* __restrict__ src,
                                                     const int* __restrict__ dst,
                                                     const int* __restrict__ bhist,
                                                     const int* __restrict__ perbhist,
                                                     int* __restrict__ gcur0,
                                                     unsigned* __restrict__ ebuf,
                                                     int n_edges, int nbuck) {
    __shared__ int scanv[MAXBUCK];
    __shared__ int hist[MAXBUCK];
    __shared__ int lbase[MAXBUCK];
    const int tid = threadIdx.x;
    const int chunk = (n_edges + BIN1B_BLOCKS - 1) / BIN1B_BLOCKS;
    const int lo = blockIdx.x * chunk;
    const int hi = min(lo + chunk, n_edges);

    int own = (tid < nbuck) ? bhist[tid] : 0;
    scanv[tid] = own;
    __syncthreads();
    #pragma unroll
    for (int off = 1; off < MAXBUCK; off <<= 1) {
        int t = (tid >= off) ? scanv[tid - off] : 0;
        __syncthreads();
        scanv[tid] += t;
        __syncthreads();
    }
    int bstart_t = scanv[tid] - own;   // exclusive
    __syncthreads();
    scanv[tid] = bstart_t;
    __syncthreads();

    if (tid < nbuck) {
        int c = perbhist[(size_t)blockIdx.x * MAXBUCK + tid];
        lbase[tid] = (c > 0) ? (scanv[tid] + atomicAdd(&gcur0[tid], c)) : 0;
        hist[tid] = 0;                 // local cursor
    }
    __syncthreads();
    for (int e = lo + tid; e < hi; e += 1024) {
        int d = dst[e];
        int bkt = d >> BSH;
        int off = atomicAdd(&hist[bkt], 1);
        ebuf[lbase[bkt] + off] = ((unsigned)src[e] << BSH) | (unsigned)(d & (BNODES - 1));
    }
}

// ---------------------------------------------------------------------------
// gemm: h = bf16( feat @ W ), persistent 3-deep async pipeline, 1024 thr.
// NEW: B ENTIRELY IN REGISTERS. Each wave's B-footprint over the whole
// kernel is fixed (brow = colgrp*16+rr, 8 k-chunks x 16 B/lane = 32 VGPR):
// load once from L2-hot Wt, delete Bs (64 KB LDS + its DMA prologue + 8
// ds_read_b128/wave/tile = ~1/3 of LDS traffic). LDS = As[3] x 32 KB = 96 KB.
// Counted-vmcnt schedule identical to r18 minus the B DMA ops (B reg-loads
// are older than every waited-on op; compiler auto-waits their first use).
// ---------------------------------------------------------------------------
__global__ __launch_bounds__(1024) void gemm_mfma(const float* __restrict__ feat,
                                                  const unsigned short* __restrict__ Wt,
                                                  unsigned short* __restrict__ h,
                                                  int n_nodes) {
    __shared__ float As[3][BM * IN_F];            // 3 x 32 KB = 96 KB

    const int tid  = threadIdx.x;
    const int wave = tid >> 6;          // 0..15
    const int lane = tid & 63;
    const int q    = lane >> 4;         // 0..3
    const int rr   = lane & 15;
    const int rowgrp = wave & 1;
    const int colgrp = wave >> 1;

    const int ntiles = (n_nodes + BM - 1) / BM;
    const int nit = ((int)blockIdx.x < ntiles)
                  ? ((ntiles - (int)blockIdx.x + GEMM_BLOCKS - 1) / GEMM_BLOCKS) : 0;

    const int brow = colgrp * 16 + rr;

    // ---- B fragments -> registers, once (global chunk (brow, k0*4+q)) ----
    bf16x8 bq[8];
    #pragma unroll
    for (int k0 = 0; k0 < 8; ++k0)
        bq[k0] = *reinterpret_cast<const bf16x8*>(
            Wt + (size_t)brow * IN_F + (k0 * 4 + q) * 8);

    // ---- prologue: stage tiles 0 and 1 ----
    #pragma unroll
    for (int pb = 0; pb < 2; ++pb) {
        if (pb < nit) {
            const int R0 = ((int)blockIdx.x + pb * GEMM_BLOCKS) * BM;
            #pragma unroll
            for (int ii = 0; ii < 2; ++ii) {
                int r  = ii * 16 + wave;
                int rg = R0 + r; if (rg >= n_nodes) rg = n_nodes - 1;
                gload_lds16(feat + (size_t)rg * IN_F + ((lane ^ (r & 7)) * 4),
                            &As[pb][r * IN_F]);
            }
        }
    }

    const int arow = rowgrp * 16 + rr;

    int t = (int)blockIdx.x;
    for (int i = 0; i < nit; ++i, t += GEMM_BLOCKS) {
        if (nit < 4)          asm volatile("s_waitcnt vmcnt(0)" ::: "memory");
        else if (i == 0)      asm volatile("s_waitcnt vmcnt(2)" ::: "memory");
        else if (i == 1)      asm volatile("s_waitcnt vmcnt(6)" ::: "memory");
        else if (i < nit - 1) asm volatile("s_waitcnt vmcnt(10)" ::: "memory");
        else                  asm volatile("s_waitcnt vmcnt(8)" ::: "memory");
        __builtin_amdgcn_s_barrier();

        // issue stage of tile i+2 into the buffer freed at iter i-1
        if (i + 2 < nit) {
            const int R0n = (t + 2 * GEMM_BLOCKS) * BM;
            float* dbuf = As[(i + 2) % 3];
            #pragma unroll
            for (int ii = 0; ii < 2; ++ii) {
                int r  = ii * 16 + wave;
                int rg = R0n + r; if (rg >= n_nodes) rg = n_nodes - 1;
                gload_lds16(feat + (size_t)rg * IN_F + ((lane ^ (r & 7)) * 4),
                            &dbuf[r * IN_F]);
            }
        }

        // compute tile t from As[i%3] (A ds_reads + MFMA only; B from regs)
        f32x4 acc = (f32x4){0.f, 0.f, 0.f, 0.f};
        const f32x4* ap = reinterpret_cast<const f32x4*>(&As[i % 3][arow * IN_F]);
        #pragma unroll
        for (int k0 = 0; k0 < 8; ++k0) {
            f32x4 a0 = ap[(k0 * 8 + 2 * q)     ^ (rr & 7)];
            f32x4 a1 = ap[(k0 * 8 + 2 * q + 1) ^ (rr & 7)];
            bf16x8 afr;
            afr[0] = (short)f2bf(a0[0]);
            afr[1] = (short)f2bf(a0[1]);
            afr[2] = (short)f2bf(a0[2]);
            afr[3] = (short)f2bf(a0[3]);
            afr[4] = (short)f2bf(a1[0]);
            afr[5] = (short)f2bf(a1[1]);
            afr[6] = (short)f2bf(a1[2]);
            afr[7] = (short)f2bf(a1[3]);
            acc = __builtin_amdgcn_mfma_f32_16x16x32_bf16(afr, bq[k0], acc, 0, 0, 0);
        }

        // exactly 4 unconditional scalar stores (h padded by BM rows)
        const int orow0 = t * BM + rowgrp * 16 + q * 4;
        const int col   = colgrp * 16 + rr;
        #pragma unroll
        for (int j = 0; j < 4; ++j)
            h[(size_t)(orow0 + j) * OUT_F + col] = f2bf(acc[j]);
    }
}

// ---------------------------------------------------------------------------
// bin2: one block per bucket; local bhist scan -> e0, per-node counts,
// 128-wide scan -> rstart + norm, exact per-node CSR. (round-18 verbatim)
// ---------------------------------------------------------------------------
__global__ __launch_bounds__(256) void bin2_kernel(const unsigned* __restrict__ ebuf,
                                                   const int* __restrict__ bhist,
                                                   int* __restrict__ rstart,
                                                   float* __restrict__ norm,
                                                   int* __restrict__ eidx,
                                                   int n_nodes, int nbuck) {
    __shared__ int bs[MAXBUCK];
    __shared__ int lcnt[BNODES];
    __shared__ int lex[BNODES];
    __shared__ int sh[256];
    const int tid = threadIdx.x;
    const int node0 = blockIdx.x << BSH;

    {
        int v[4], s = 0;
        #pragma unroll
        for (int j = 0; j < 4; ++j) {
            int idx = tid * 4 + j;
            v[j] = (idx < nbuck) ? bhist[idx] : 0;
            s += v[j];
        }
        sh[tid] = s;
        __syncthreads();
        #pragma unroll
        for (int off = 1; off < 256; off <<= 1) {
            int t = (tid >= off) ? sh[tid - off] : 0;
            __syncthreads();
            sh[tid] += t;
            __syncthreads();
        }
        int ex = sh[tid] - s;
        #pragma unroll
        for (int j = 0; j < 4; ++j) {
            bs[tid * 4 + j] = ex;
            ex += v[j];
        }
    }
    __syncthreads();

    const int e0 = bs[blockIdx.x];
    const int e1 = e0 + bhist[blockIdx.x];

    if (tid < BNODES) lcnt[tid] = 0;
    __syncthreads();
    for (int e = e0 + tid; e < e1; e += 256)
        atomicAdd(&lcnt[ebuf[e] & (BNODES - 1)], 1);
    __syncthreads();

    int own = (tid < BNODES) ? lcnt[tid] : 0;
    if (tid < BNODES) lex[tid] = own;
    __syncthreads();
    #pragma unroll
    for (int off = 1; off < BNODES; off <<= 1) {
        int t = (tid >= off && tid < BNODES) ? lex[tid - off] : 0;
        __syncthreads();
        if (tid < BNODES) lex[tid] += t;
        __syncthreads();
    }
    if (tid < BNODES) {
        int ex = lex[tid] - own;
        lex[tid] = ex;
        int g = node0 + tid;
        if (g <= n_nodes) rstart[g] = e0 + ex;
        if (g < n_nodes) {
            float d = (float)own;
            if (d < 1.0f) d = 1.0f;
            norm[g] = 1.0f / sqrtf(d);
        }
        lcnt[tid] = 0;                 // reuse as cursor
    }
    __syncthreads();

    for (int e = e0 + tid; e < e1; e += 256) {
        unsigned pk = ebuf[e];
        int dl = pk & (BNODES - 1);
        int pos = atomicAdd(&lcnt[dl], 1);
        eidx[e0 + lex[dl] + pos] = (int)(pk >> BSH);
    }
}

// ---------------------------------------------------------------------------
// agg: one wave per dst node, 4 edge-slots x 16 lanes, uniform control flow.
// (unchanged — fabric-limited at ~64 us)
// ---------------------------------------------------------------------------
__global__ __launch_bounds__(256) void agg_kernel(const unsigned short* __restrict__ h,
                                                  const int* __restrict__ eidx,
                                                  const int* __restrict__ rstart,
                                                  const float* __restrict__ norm,
                                                  const float* __restrict__ bias,
                                                  float* __restrict__ out,
                                                  int n_nodes) {
    const int wave = threadIdx.x >> 6;
    const int lane = threadIdx.x & 63;
    const int grp  = lane >> 4;
    const int gl   = lane & 15;
    const int node = blockIdx.x * 4 + wave;
    if (node >= n_nodes) return;

    const int start = rstart[node];
    const int cnt   = rstart[node + 1] - start;
    const unsigned short* __restrict__ hb = h + gl * 8;

    float acc[8] = {0.f, 0.f, 0.f, 0.f, 0.f, 0.f, 0.f, 0.f};

    for (int base = 0; base < cnt; base += 64) {
        const int rem = min(64, cnt - base);
        int   ev = (lane < rem) ? eidx[start + base + lane] : 0;
        float nv = (lane < rem) ? norm[ev] : 0.f;

        int j = 0;
        for (; j + 16 <= rem; j += 16) {
            int   s0 = __shfl(ev, j + grp);
            int   s1 = __shfl(ev, j + grp + 4);
            int   s2 = __shfl(ev, j + grp + 8);
            int   s3 = __shfl(ev, j + grp + 12);
            float n0 = __shfl(nv, j + grp);
            float n1 = __shfl(nv, j + grp + 4);
            float n2 = __shfl(nv, j + grp + 8);
            float n3 = __shfl(nv, j + grp + 12);
            us8 v0 = *reinterpret_cast<const us8*>(hb + (size_t)s0 * OUT_F);
            us8 v1 = *reinterpret_cast<const us8*>(hb + (size_t)s1 * OUT_F);
            us8 v2 = *reinterpret_cast<const us8*>(hb + (size_t)s2 * OUT_F);
            us8 v3 = *reinterpret_cast<const us8*>(hb + (size_t)s3 * OUT_F);
            #pragma unroll
            for (int qq = 0; qq < 8; ++qq) {
                acc[qq] += bf2f(v0[qq]) * n0 + bf2f(v1[qq]) * n1
                         + bf2f(v2[qq]) * n2 + bf2f(v3[qq]) * n3;
            }
        }
        for (; j < rem; j += 4) {
            int   je = j + grp;
            int   jc = min(je, rem - 1);
            int   s  = __shfl(ev, jc);
            float nm = __shfl(nv, jc);
            if (je >= rem) nm = 0.f;
            us8 v = *reinterpret_cast<const us8*>(hb + (size_t)s * OUT_F);
            #pragma unroll
            for (int qq = 0; qq < 8; ++qq)
                acc[qq] += bf2f(v[qq]) * nm;
        }
    }

    #pragma unroll
    for (int qq = 0; qq < 8; ++qq) {
        acc[qq] += __shfl_xor(acc[qq], 16);
        acc[qq] += __shfl_xor(acc[qq], 32);
    }

    if (grp == 0) {
        const float nd = norm[node];
        const float4 b0 = *reinterpret_cast<const float4*>(bias + gl * 8);
        const float4 b1 = *reinterpret_cast<const float4*>(bias + gl * 8 + 4);
        float4 r0, r1;
        r0.x = acc[0] * nd + b0.x;
        r0.y = acc[1] * nd + b0.y;
        r0.z = acc[2] * nd + b0.z;
        r0.w = acc[3] * nd + b0.w;
        r1.x = acc[4] * nd + b1.x;
        r1.y = acc[5] * nd + b1.y;
        r1.z = acc[6] * nd + b1.z;
        r1.w = acc[7] * nd + b1.w;
        float* o = out + (size_t)node * OUT_F + gl * 8;
        *reinterpret_cast<float4*>(o)     = r0;
        *reinterpret_cast<float4*>(o + 4) = r1;
    }
}

// ---------------------------------------------------------------------------
extern "C" void kernel_launch(void* const* d_in, const int* in_sizes, int n_in,
                              void* d_out, int out_size, void* d_ws, size_t ws_size,
                              hipStream_t stream) {
    const float* feat   = (const float*)d_in[0];
    const float* weight = (const float*)d_in[1];
    const float* bias   = (const float*)d_in[2];
    const int*   src    = (const int*)d_in[3];
    const int*   dst    = (const int*)d_in[4];
    float* out = (float*)d_out;

    const int n_nodes = in_sizes[0] / IN_F;
    const int n_edges = in_sizes[3];
    const int nbuck   = (n_nodes + BNODES - 1) >> BSH;

    char* ws = (char*)d_ws;
    size_t off = 0;
    auto alloc = [&](size_t bytes) {
        char* p = ws + off;
        off += (bytes + 15) & ~(size_t)15;
        return p;
    };
    unsigned short* h  = (unsigned short*)alloc((size_t)(n_nodes + BM) * OUT_F * 2); // +BM pad rows
    float* norm        = (float*)alloc((size_t)n_nodes * 4);
    int*   rstart      = (int*)alloc(((size_t)n_nodes + 1) * 4);
    int*   bhist       = (int*)alloc(2 * MAXBUCK * 4);   // bhist | gcur0
    int*   gcur0       = bhist + MAXBUCK;
    int*   perbhist    = (int*)alloc((size_t)BIN1A_BLOCKS * MAXBUCK * 4);  // 1 MB
    unsigned short* Wt = (unsigned short*)alloc((size_t)OUT_F * IN_F * 2);
    unsigned* ebuf     = (unsigned*)alloc((size_t)n_edges * 4);
    int*   eidx        = (int*)alloc((size_t)n_edges * 4);

    hipMemsetAsync(bhist, 0, 2 * MAXBUCK * sizeof(int), stream);
    // K1: bin1a (+perbhist) || wprep
    prep_kernel<<<BIN1A_BLOCKS + OUT_F, 256, 0, stream>>>(weight, Wt, dst, bhist,
                                                          perbhist, n_edges, nbuck);
    // K2: gemm (3-deep counted-vmcnt pipeline, B in registers, 96 KB LDS)
    gemm_mfma<<<GEMM_BLOCKS, 1024, 0, stream>>>(feat, Wt, h, n_nodes);
    // K3: binning into bucket-grouped ebuf
    bin1b_kernel<<<BIN1B_BLOCKS, 1024, 0, stream>>>(src, dst, bhist, perbhist,
                                                    gcur0, ebuf, n_edges, nbuck);
    // K4: exact CSR
    bin2_kernel<<<nbuck, 256, 0, stream>>>(ebuf, bhist, rstart, norm, eidx,
                                           n_nodes, nbuck);
    // K5: aggregate
    agg_kernel<<<(n_nodes + 3) / 4, 256, 0, stream>>>(h, eidx, rstart, norm, bias, out, n_nodes);
}